// Round 1
// baseline (450.047 us; speedup 1.0000x reference)
//
#include <hip/hip_runtime.h>
#include <hip/hip_bf16.h>

#define BB 8
#define FF 4096
#define SS 1024
#define DD 128
#define DLL 256
#define NF (BB*FF)    // 32768 facts
#define FPB 8         // facts per block

__device__ __forceinline__ float gelu_exact(float x) {
    return 0.5f * x * (1.0f + erff(x * 0.70710678118654752440f));
}

// ---------------------------------------------------------------------------
// Kernel 1: gather + two message MLPs per fact + atomic scatter-add into agg
// block = 256 threads, FPB facts per block.
// ---------------------------------------------------------------------------
__global__ __launch_bounds__(256) void msg_kernel(
    const int* __restrict__ a0, const int* __restrict__ a1,
    const int* __restrict__ pidx, const float* __restrict__ bidir,
    const float* __restrict__ pos_emb, const float* __restrict__ pred_emb,
    const float* __restrict__ w1, const float* __restrict__ b1,
    const float* __restrict__ w2, const float* __restrict__ b2,
    float* __restrict__ agg)
{
    __shared__ float xs[FPB][384];       // segs: [na0 | pe | na1] per fact
    __shared__ float h1s[2*FPB][256];    // message m = 2f+parity (0=msg01,1=msg10)

    const int tid = threadIdx.x;
    const int fbase = blockIdx.x * FPB;

    // ---- stage gathered inputs ----
    for (int q = tid; q < FPB * 384; q += 256) {
        int f = q / 384, r = q - f * 384;
        int seg = r >> 7, d = r & 127;
        int g = fbase + f;
        const float* src;
        if (seg == 0)      src = pos_emb + a0[g] * DD;
        else if (seg == 1) src = pred_emb + pidx[g] * DD;
        else               src = pos_emb + a1[g] * DD;
        xs[f][r] = src[d];
    }
    __syncthreads();

    // ---- GEMM1: h1[m][j] = gelu(b1[j] + sum_k x[m][k]*w1[k][j]) ----
    const int j = tid;   // 0..255
    float acc01[FPB], acc10[FPB];
    const float bj = b1[j];
    #pragma unroll
    for (int f = 0; f < FPB; ++f) { acc01[f] = bj; acc10[f] = bj; }

    for (int k = 0; k < 384; k += 4) {
        const float wa = w1[(k+0)*256 + j];
        const float wb = w1[(k+1)*256 + j];
        const float wc = w1[(k+2)*256 + j];
        const float wd = w1[(k+3)*256 + j];
        const int seg = k >> 7;
        const int k10 = (seg == 0) ? (k + 256) : ((seg == 2) ? (k - 256) : k);
        #pragma unroll
        for (int f = 0; f < FPB; ++f) {
            const float4 x01 = *(const float4*)&xs[f][k];
            const float4 x10 = *(const float4*)&xs[f][k10];
            acc01[f] += x01.x*wa + x01.y*wb + x01.z*wc + x01.w*wd;
            acc10[f] += x10.x*wa + x10.y*wb + x10.z*wc + x10.w*wd;
        }
    }
    #pragma unroll
    for (int f = 0; f < FPB; ++f) {
        h1s[2*f+0][j] = gelu_exact(acc01[f]);
        h1s[2*f+1][j] = gelu_exact(acc10[f]);
    }
    __syncthreads();

    // ---- GEMM2 + scatter: msg[m][d] = b2[d] + sum_k h1[m][k]*w2[k][d] ----
    const int d = tid & 127;
    const int parity = tid >> 7;     // 0 -> msg01 (to a1), 1 -> msg10 (to a0, *bidir)
    float acc2[FPB];
    #pragma unroll
    for (int i = 0; i < FPB; ++i) acc2[i] = 0.0f;

    for (int k = 0; k < 256; k += 4) {
        const float wv0 = w2[(k+0)*128 + d];
        const float wv1 = w2[(k+1)*128 + d];
        const float wv2 = w2[(k+2)*128 + d];
        const float wv3 = w2[(k+3)*128 + d];
        #pragma unroll
        for (int i = 0; i < FPB; ++i) {
            const float4 h4 = *(const float4*)&h1s[2*i + parity][k];
            acc2[i] += h4.x*wv0 + h4.y*wv1 + h4.z*wv2 + h4.w*wv3;
        }
    }
    const float bd = b2[d];
    #pragma unroll
    for (int i = 0; i < FPB; ++i) {
        const int g = fbase + i;
        const int b = g >> 12;  // g / FF
        float v = acc2[i] + bd;
        int node;
        if (parity) { v *= bidir[g]; node = a0[g]; }
        else        { node = a1[g]; }
        atomicAdd(&agg[(b*SS + node)*DD + d], v);
    }
}

// ---------------------------------------------------------------------------
// Kernel 2: h = pos_emb + agg -> LayerNorm -> accumulate pooled sums per (b,d)
// one row per wave (128 elems -> 2/lane), 32 rows per block, one b per block.
// ---------------------------------------------------------------------------
__global__ __launch_bounds__(256) void ln_pool_kernel(
    const float* __restrict__ pos_emb, const float* __restrict__ agg,
    const float* __restrict__ ln_g, const float* __restrict__ ln_b,
    float* __restrict__ pooled)
{
    const int b = blockIdx.x / (SS / 32);
    const int s0 = (blockIdx.x % (SS / 32)) * 32;
    const int wave = threadIdx.x >> 6;
    const int lane = threadIdx.x & 63;

    const float g0 = ln_g[lane], g1 = ln_g[lane + 64];
    const float bb0 = ln_b[lane], bb1 = ln_b[lane + 64];

    float accp0 = 0.0f, accp1 = 0.0f;
    for (int r = 0; r < 8; ++r) {
        const int s = s0 + wave * 8 + r;
        const float* aggrow = agg + (size_t)(b*SS + s) * DD;
        const float* noderow = pos_emb + s * DD;
        const float h0 = noderow[lane]      + aggrow[lane];
        const float h1 = noderow[lane + 64] + aggrow[lane + 64];

        float sum = h0 + h1;
        #pragma unroll
        for (int o = 32; o > 0; o >>= 1) sum += __shfl_xor(sum, o);
        const float mu = sum * (1.0f / 128.0f);

        const float d0 = h0 - mu, d1 = h1 - mu;
        float sq = d0*d0 + d1*d1;
        #pragma unroll
        for (int o = 32; o > 0; o >>= 1) sq += __shfl_xor(sq, o);
        const float rstd = rsqrtf(sq * (1.0f / 128.0f) + 1e-5f);

        accp0 += d0 * rstd * g0 + bb0;
        accp1 += d1 * rstd * g1 + bb1;
    }

    __shared__ float red[4][128];
    red[wave][lane]      = accp0;
    red[wave][lane + 64] = accp1;
    __syncthreads();
    if (threadIdx.x < 128) {
        const float v = red[0][threadIdx.x] + red[1][threadIdx.x]
                      + red[2][threadIdx.x] + red[3][threadIdx.x];
        atomicAdd(&pooled[b*DD + threadIdx.x], v);
    }
}

// ---------------------------------------------------------------------------
// Kernel 3: latent head. one block per b; thread j owns output column j.
// ---------------------------------------------------------------------------
__global__ __launch_bounds__(256) void head_kernel(
    const float* __restrict__ pooled,
    const float* __restrict__ lw1, const float* __restrict__ lb1,
    const float* __restrict__ lw2, const float* __restrict__ lb2,
    float* __restrict__ out)
{
    const int b = blockIdx.x;
    const int j = threadIdx.x;
    __shared__ float p[128];
    __shared__ float t1[256];
    if (j < 128) p[j] = pooled[b*DD + j] * (1.0f / (float)SS);
    __syncthreads();

    float acc = lb1[j];
    for (int k = 0; k < 128; ++k) acc += p[k] * lw1[k*256 + j];
    t1[j] = gelu_exact(acc);
    __syncthreads();

    float acc2 = lb2[j];
    for (int k = 0; k < 256; ++k) acc2 += t1[k] * lw2[k*256 + j];
    out[b*DLL + j] = acc2;
}

extern "C" void kernel_launch(void* const* d_in, const int* in_sizes, int n_in,
                              void* d_out, int out_size, void* d_ws, size_t ws_size,
                              hipStream_t stream) {
    const int*   a0       = (const int*)d_in[0];
    const int*   a1       = (const int*)d_in[1];
    const int*   pidx     = (const int*)d_in[2];
    const float* bidir    = (const float*)d_in[3];
    const float* pos_emb  = (const float*)d_in[4];
    const float* pred_emb = (const float*)d_in[5];
    const float* w1       = (const float*)d_in[6];
    const float* b1       = (const float*)d_in[7];
    const float* w2       = (const float*)d_in[8];
    const float* b2       = (const float*)d_in[9];
    const float* ln_g     = (const float*)d_in[10];
    const float* ln_b     = (const float*)d_in[11];
    const float* lw1      = (const float*)d_in[12];
    const float* lb1      = (const float*)d_in[13];
    const float* lw2      = (const float*)d_in[14];
    const float* lb2      = (const float*)d_in[15];

    float* agg    = (float*)d_ws;                      // B*S*D floats = 4 MB
    float* pooled = (float*)d_ws + (size_t)BB*SS*DD;   // B*D floats

    hipMemsetAsync(d_ws, 0, ((size_t)BB*SS*DD + BB*DD) * sizeof(float), stream);

    msg_kernel<<<NF/FPB, 256, 0, stream>>>(a0, a1, pidx, bidir, pos_emb, pred_emb,
                                           w1, b1, w2, b2, agg);
    ln_pool_kernel<<<BB*(SS/32), 256, 0, stream>>>(pos_emb, agg, ln_g, ln_b, pooled);
    head_kernel<<<BB, 256, 0, stream>>>(pooled, lw1, lb1, lw2, lb2, (float*)d_out);
}

// Round 2
// 88.192 us; speedup vs baseline: 5.1030x; 5.1030x over previous
//
#include <hip/hip_runtime.h>
#include <hip/hip_bf16.h>

#define BB 8
#define FF 4096
#define SS 1024
#define DD 128
#define DLL 256
#define NF (BB*FF)     // 32768 facts
#define FPB 32         // facts per msg block (64 messages)

typedef short  short8 __attribute__((ext_vector_type(8)));
typedef float  f32x4  __attribute__((ext_vector_type(4)));

__device__ __forceinline__ float gelu_exact(float x) {
    return 0.5f * x * (1.0f + erff(x * 0.70710678118654752440f));
}

__device__ __forceinline__ ushort f2bf(float x) {
    uint u = __float_as_uint(x);
    uint r = (u + 0x7fffu + ((u >> 16) & 1u)) >> 16;
    return (ushort)r;
}

// ---------------------------------------------------------------------------
// Prep: convert embeddings to bf16; build bf16 w1T[256][384], w2T[128][256].
// ---------------------------------------------------------------------------
#define N_POS   (SS*DD)            // 131072
#define N_PRED_ (14*DD)            // 1792
#define N_W1    (384*256)          // 98304
#define N_W2    (256*128)          // 32768
#define N_PREP  (N_POS + N_PRED_ + N_W1 + N_W2)

__global__ __launch_bounds__(256) void prep_kernel(
    const float* __restrict__ pos, const float* __restrict__ pred,
    const float* __restrict__ w1,  const float* __restrict__ w2,
    ushort* __restrict__ pos_bf, ushort* __restrict__ pred_bf,
    ushort* __restrict__ w1T,    ushort* __restrict__ w2T)
{
    int i = blockIdx.x * 256 + threadIdx.x;
    if (i < N_POS) { pos_bf[i] = f2bf(pos[i]); return; }
    i -= N_POS;
    if (i < N_PRED_) { pred_bf[i] = f2bf(pred[i]); return; }
    i -= N_PRED_;
    if (i < N_W1) { int k = i >> 8, n = i & 255; w1T[n*384 + k] = f2bf(w1[i]); return; }
    i -= N_W1;
    if (i < N_W2) { int k = i >> 7, d = i & 127; w2T[d*256 + k] = f2bf(w2[i]); return; }
}

// ---------------------------------------------------------------------------
// Kernel 1 (MFMA): 32 facts / 64 messages per block, 4 waves.
//   GEMM1: [64 x 384] x [384 x 256] -> gelu -> h1 (bf16, LDS)
//   GEMM2: [64 x 256] x [256 x 128] -> +b2, *bidir, atomic scatter into agg
// msg row m = 2*f + p  (p=0: [na0|pe|na1] -> a1 ; p=1: [na1|pe|na0] -> a0*bidir)
// ---------------------------------------------------------------------------
__global__ __launch_bounds__(256) void msg_kernel(
    const int* __restrict__ a0, const int* __restrict__ a1,
    const int* __restrict__ pidx, const float* __restrict__ bidir,
    const ushort* __restrict__ pos_bf, const ushort* __restrict__ pred_bf,
    const ushort* __restrict__ w1T, const float* __restrict__ b1,
    const ushort* __restrict__ w2T, const float* __restrict__ b2,
    float* __restrict__ agg)
{
    __shared__ uint4 xs4[FPB * 48];   // 32 facts x 384 bf16 (48 x 16B units), XOR-swizzled
    __shared__ uint4 h1s4[64 * 32];   // 64 msgs x 256 bf16 (32 x 16B units), XOR-swizzled
    __shared__ int   sa0[FPB], sa1[FPB], spi[FPB];
    __shared__ float sbid[FPB];

    const int tid = threadIdx.x;
    const int fbase = blockIdx.x * FPB;
    const int wid = tid >> 6, lane = tid & 63;
    const int lq = lane >> 4, lr = lane & 15;

    if (tid < FPB) {
        int g = fbase + tid;
        sa0[tid] = a0[g]; sa1[tid] = a1[g]; spi[tid] = pidx[g]; sbid[tid] = bidir[g];
    }
    __syncthreads();

    // ---- stage gathered inputs (bf16, 16B units, swizzled by fact&7) ----
    for (int U = tid; U < FPB * 48; U += 256) {
        int f = U / 48, u = U - 48 * f;
        int seg = u >> 4, du = u & 15;
        int row = (seg == 0) ? sa0[f] : ((seg == 1) ? spi[f] : sa1[f]);
        const uint4* src = (const uint4*)(((seg == 1) ? pred_bf : pos_bf) + row * DD) + du;
        xs4[f * 48 + (u ^ (f & 7))] = *src;
    }
    __syncthreads();

    // ---- GEMM1 ----
    f32x4 acc[4][4];
    #pragma unroll
    for (int mf = 0; mf < 4; ++mf)
        #pragma unroll
        for (int nf = 0; nf < 4; ++nf) acc[mf][nf] = (f32x4)0.0f;

    const int factL = lr >> 1;       // fact low bits (0..7)
    const int par   = lr & 1;        // message parity

    for (int ks = 0; ks < 12; ++ks) {
        const int k_el = ks * 32 + lq * 8;
        const int seg = ks >> 2;
        const int kp = k_el + (par ? (seg == 0 ? 256 : (seg == 2 ? -256 : 0)) : 0);
        const int uq = (kp >> 3) ^ factL;
        short8 a[4];
        #pragma unroll
        for (int mf = 0; mf < 4; ++mf)
            a[mf] = *(const short8*)&xs4[(mf * 8 + factL) * 48 + uq];
        short8 b[4];
        #pragma unroll
        for (int nf = 0; nf < 4; ++nf)
            b[nf] = *(const short8*)(w1T + (wid * 64 + nf * 16 + lr) * 384 + k_el);
        #pragma unroll
        for (int mf = 0; mf < 4; ++mf)
            #pragma unroll
            for (int nf = 0; nf < 4; ++nf)
                acc[mf][nf] = __builtin_amdgcn_mfma_f32_16x16x32_bf16(a[mf], b[nf], acc[mf][nf], 0, 0, 0);
    }

    // ---- gelu + store h1 as bf16 (swizzled) ----
    {
        float bj[4];
        #pragma unroll
        for (int nf = 0; nf < 4; ++nf) bj[nf] = b1[wid * 64 + nf * 16 + lr];
        #pragma unroll
        for (int mf = 0; mf < 4; ++mf) {
            #pragma unroll
            for (int nf = 0; nf < 4; ++nf) {
                #pragma unroll
                for (int r = 0; r < 4; ++r) {
                    float v = gelu_exact(acc[mf][nf][r] + bj[nf]);
                    int row = mf * 16 + lq * 4 + r;
                    int c = wid * 64 + nf * 16 + lr;
                    int byteoff = row * 512 + (((c >> 3) ^ (row & 15)) << 4) + (c & 7) * 2;
                    *(ushort*)((char*)h1s4 + byteoff) = f2bf(v);
                }
            }
        }
    }
    __syncthreads();

    // ---- GEMM2 ----
    f32x4 acc2[4][2];
    #pragma unroll
    for (int mf = 0; mf < 4; ++mf)
        #pragma unroll
        for (int nf = 0; nf < 2; ++nf) acc2[mf][nf] = (f32x4)0.0f;

    for (int ks = 0; ks < 8; ++ks) {
        const int u = ks * 4 + lq;
        short8 a2[4];
        #pragma unroll
        for (int mf = 0; mf < 4; ++mf) {
            int row = mf * 16 + lr;
            a2[mf] = *(const short8*)((char*)h1s4 + row * 512 + ((u ^ (row & 15)) << 4));
        }
        short8 b2v[2];
        #pragma unroll
        for (int nf = 0; nf < 2; ++nf)
            b2v[nf] = *(const short8*)(w2T + (wid * 32 + nf * 16 + lr) * 256 + ks * 32 + lq * 8);
        #pragma unroll
        for (int mf = 0; mf < 4; ++mf)
            #pragma unroll
            for (int nf = 0; nf < 2; ++nf)
                acc2[mf][nf] = __builtin_amdgcn_mfma_f32_16x16x32_bf16(a2[mf], b2v[nf], acc2[mf][nf], 0, 0, 0);
    }

    // ---- bias + bidir + scatter ----
    {
        float bd[2];
        #pragma unroll
        for (int nf = 0; nf < 2; ++nf) bd[nf] = b2[wid * 32 + nf * 16 + lr];
        #pragma unroll
        for (int mf = 0; mf < 4; ++mf) {
            #pragma unroll
            for (int r = 0; r < 4; ++r) {
                int f = mf * 8 + lq * 2 + (r >> 1);
                int p = r & 1;
                int node = p ? sa0[f] : sa1[f];
                float scale = p ? sbid[f] : 1.0f;
                int g = fbase + f;
                int bidx = g >> 12;
                float* dst = agg + ((size_t)((bidx << 10) + node)) * DD;
                #pragma unroll
                for (int nf = 0; nf < 2; ++nf) {
                    int d = wid * 32 + nf * 16 + lr;
                    float v = (acc2[mf][nf][r] + bd[nf]) * scale;
                    atomicAdd(dst + d, v);
                }
            }
        }
    }
}

// ---------------------------------------------------------------------------
// Kernel 2: h = pos_emb + agg -> LayerNorm -> pooled sums per (b,d)
// ---------------------------------------------------------------------------
__global__ __launch_bounds__(256) void ln_pool_kernel(
    const float* __restrict__ pos_emb, const float* __restrict__ agg,
    const float* __restrict__ ln_g, const float* __restrict__ ln_b,
    float* __restrict__ pooled)
{
    const int b = blockIdx.x / (SS / 32);
    const int s0 = (blockIdx.x % (SS / 32)) * 32;
    const int wave = threadIdx.x >> 6;
    const int lane = threadIdx.x & 63;

    const float g0 = ln_g[lane], g1 = ln_g[lane + 64];
    const float bb0 = ln_b[lane], bb1 = ln_b[lane + 64];

    float accp0 = 0.0f, accp1 = 0.0f;
    for (int r = 0; r < 8; ++r) {
        const int s = s0 + wave * 8 + r;
        const float* aggrow = agg + (size_t)(b*SS + s) * DD;
        const float* noderow = pos_emb + s * DD;
        const float h0 = noderow[lane]      + aggrow[lane];
        const float h1 = noderow[lane + 64] + aggrow[lane + 64];

        float sum = h0 + h1;
        #pragma unroll
        for (int o = 32; o > 0; o >>= 1) sum += __shfl_xor(sum, o);
        const float mu = sum * (1.0f / 128.0f);

        const float d0 = h0 - mu, d1 = h1 - mu;
        float sq = d0*d0 + d1*d1;
        #pragma unroll
        for (int o = 32; o > 0; o >>= 1) sq += __shfl_xor(sq, o);
        const float rstd = rsqrtf(sq * (1.0f / 128.0f) + 1e-5f);

        accp0 += d0 * rstd * g0 + bb0;
        accp1 += d1 * rstd * g1 + bb1;
    }

    __shared__ float red[4][128];
    red[wave][lane]      = accp0;
    red[wave][lane + 64] = accp1;
    __syncthreads();
    if (threadIdx.x < 128) {
        const float v = red[0][threadIdx.x] + red[1][threadIdx.x]
                      + red[2][threadIdx.x] + red[3][threadIdx.x];
        atomicAdd(&pooled[b*DD + threadIdx.x], v);
    }
}

// ---------------------------------------------------------------------------
// Kernel 3: latent head
// ---------------------------------------------------------------------------
__global__ __launch_bounds__(256) void head_kernel(
    const float* __restrict__ pooled,
    const float* __restrict__ lw1, const float* __restrict__ lb1,
    const float* __restrict__ lw2, const float* __restrict__ lb2,
    float* __restrict__ out)
{
    const int b = blockIdx.x;
    const int j = threadIdx.x;
    __shared__ float p[128];
    __shared__ float t1[256];
    if (j < 128) p[j] = pooled[b*DD + j] * (1.0f / (float)SS);
    __syncthreads();

    float acc = lb1[j];
    for (int k = 0; k < 128; ++k) acc += p[k] * lw1[k*256 + j];
    t1[j] = gelu_exact(acc);
    __syncthreads();

    float acc2 = lb2[j];
    for (int k = 0; k < 256; ++k) acc2 += t1[k] * lw2[k*256 + j];
    out[b*DLL + j] = acc2;
}

extern "C" void kernel_launch(void* const* d_in, const int* in_sizes, int n_in,
                              void* d_out, int out_size, void* d_ws, size_t ws_size,
                              hipStream_t stream) {
    const int*   a0       = (const int*)d_in[0];
    const int*   a1       = (const int*)d_in[1];
    const int*   pidx     = (const int*)d_in[2];
    const float* bidir    = (const float*)d_in[3];
    const float* pos_emb  = (const float*)d_in[4];
    const float* pred_emb = (const float*)d_in[5];
    const float* w1       = (const float*)d_in[6];
    const float* b1       = (const float*)d_in[7];
    const float* w2       = (const float*)d_in[8];
    const float* b2       = (const float*)d_in[9];
    const float* ln_g     = (const float*)d_in[10];
    const float* ln_b     = (const float*)d_in[11];
    const float* lw1      = (const float*)d_in[12];
    const float* lb1      = (const float*)d_in[13];
    const float* lw2      = (const float*)d_in[14];
    const float* lb2      = (const float*)d_in[15];

    char* ws = (char*)d_ws;
    float*  agg     = (float*)ws;                               // 4 MB
    float*  pooled  = (float*)(ws + 4194304);                   // 4 KB
    ushort* pos_bf  = (ushort*)(ws + 4198400);                  // 256 KB
    ushort* pred_bf = (ushort*)(ws + 4460544);                  // 3.5 KB
    ushort* w1T     = (ushort*)(ws + 4464128);                  // 192 KB
    ushort* w2T     = (ushort*)(ws + 4660736);                  // 64 KB

    hipMemsetAsync(d_ws, 0, 4198400, stream);
    prep_kernel<<<(N_PREP + 255) / 256, 256, 0, stream>>>(
        pos_emb, pred_emb, w1, w2, pos_bf, pred_bf, w1T, w2T);

    msg_kernel<<<NF / FPB, 256, 0, stream>>>(a0, a1, pidx, bidir,
                                             pos_bf, pred_bf, w1T, b1, w2T, b2, agg);
    ln_pool_kernel<<<BB * (SS / 32), 256, 0, stream>>>(pos_emb, agg, ln_g, ln_b, pooled);
    head_kernel<<<BB, 256, 0, stream>>>(pooled, lw1, lb1, lw2, lb2, (float*)d_out);
}